// Round 8
// baseline (275.912 us; speedup 1.0000x reference)
//
#include <hip/hip_runtime.h>
#include <hip/hip_cooperative_groups.h>

namespace cg = cooperative_groups;

typedef float f32x2 __attribute__((ext_vector_type(2)));

#define HWPIX 589824
#define Wdim 768
#define Bdim 4
#define Kdim 16
#define NBINS 2048
#define RANGE_F 16.0f
#define BIN_W (RANGE_F / NBINS)
#define INV_BIN_W (NBINS / RANGE_F)
#define EPSf 1e-6f
#define QCLIP 13.8155106f   /* -log(1e-6): q >= QCLIP  <=>  phi clamps to EPS */

#define Q4 (HWPIX / 4)      // 147456 float4 groups per channel
#define NBLK 768            // 3 blocks/CU on 256 CUs
#define NSB 192             // blocks per batch
#define GPI (NSB * 256)     // float4-groups per iteration per batch

// ws float offsets
#define ACC_OFF 0                      // [B][K][5]
#define LOVARR_OFF 724                 // [64]
#define HIST_OFF_F 1024                // uint hist[B*K][2][NBINS]
#define NHIST (Bdim * Kdim * 2 * NBINS)
#define SPART_OFF (HIST_OFF_F + NHIST + 64)        // float [NBLK][80]
#define MPART_OFF (SPART_OFF + NBLK * 80)          // float [NBLK][2]

// ======================= phase bodies (shared by both paths) ================

__device__ __forceinline__ void phaseA(const float* __restrict__ yp,
                                       const int* __restrict__ yt,
                                       float* __restrict__ ws,
                                       unsigned* __restrict__ hist,
                                       int blk, int tid) {
    int lane = tid & 63, wv = tid >> 6;
    __shared__ float lpart[4][80];
    int b = blk / NSB, xblk = blk - b * NSB;
    const float4* bp4 = (const float4*)(yp + (size_t)b * 5 * HWPIX);
    const int4* bt4 = (const int4*)(yt + (size_t)b * HWPIX);

    // zero hist + posnh (grid-stride: NBLK*256 threads cover NHIST+64)
    for (int i = blk * 256 + tid; i < NHIST + 64; i += NBLK * 256) hist[i] = 0u;

    f32x2 acc2[40];
#pragma unroll
    for (int v = 0; v < 40; ++v) acc2[v] = (f32x2){0.f, 0.f};

    for (int p = 0; p < 3; ++p) {
        int g = p * GPI + xblk * 256 + tid;
        float4 voy = bp4[g];
        float4 vox = bp4[g + Q4];
        float4 vsy = bp4[g + 2 * Q4];
        float4 vsx = bp4[g + 3 * Q4];
        int4 vt = bt4[g];
        int hwb = g * 4;
        float oy[4] = {voy.x, voy.y, voy.z, voy.w};
        float ox[4] = {vox.x, vox.y, vox.z, vox.w};
        float sy[4] = {vsy.x, vsy.y, vsy.z, vsy.w};
        float sx[4] = {vsx.x, vsx.y, vsx.z, vsx.w};
        int tt[4] = {vt.x, vt.y, vt.z, vt.w};
#pragma unroll
        for (int j = 0; j < 4; ++j) {
            int hw = hwb + j;
            int h = hw / Wdim;
            int w = hw - h * Wdim;
            int own = tt[j] - 1;
            float vy = (float)h + oy[j];
            float vx = (float)w + ox[j];
#pragma unroll
            for (int q = 0; q < 8; ++q) {
                f32x2 m2 = {(own == 2 * q) ? 1.0f : 0.0f,
                            (own == 2 * q + 1) ? 1.0f : 0.0f};
                acc2[q * 5 + 0] += m2;
                acc2[q * 5 + 1] += m2 * vy;
                acc2[q * 5 + 2] += m2 * vx;
                acc2[q * 5 + 3] += m2 * sy[j];
                acc2[q * 5 + 4] += m2 * sx[j];
            }
        }
    }

#define ACCV(v) (acc2[((v) / 5 / 2) * 5 + (v) % 5][((v) / 5) & 1])
    bool lo = (lane < 32);
#pragma unroll
    for (int v = 0; v < 40; ++v) {
        float send = lo ? ACCV(v + 40) : ACCV(v);
        float got = __shfl_xor(send, 32);
        ACCV(v) += lo ? got : 0.f;
        ACCV(v + 40) += lo ? 0.f : got;
    }
#pragma unroll
    for (int v = 0; v < 40; ++v) {
        float x = lo ? ACCV(v) : ACCV(v + 40);
#pragma unroll
        for (int o = 16; o >= 1; o >>= 1) x += __shfl_xor(x, o);
        if ((lane & 31) == 0) lpart[wv][lo ? v : v + 40] = x;
    }
#undef ACCV
    __syncthreads();
    if (tid < 80) {
        float v = lpart[0][tid] + lpart[1][tid] + lpart[2][tid] + lpart[3][tid];
        ws[SPART_OFF + (size_t)blk * 80 + tid] = v;
    }
}

__device__ __forceinline__ void phaseB(float* __restrict__ ws, int blk, int tid) {
    if (blk >= 80) return;
    int wv = tid >> 6, lane = tid & 63;
    int gw = blk * 4 + wv;            // 0..319
    int bb = gw / 80, idx = gw - bb * 80;
    const float* sp = ws + SPART_OFF + (size_t)bb * NSB * 80 + idx;
    float x = sp[(size_t)lane * 80] + sp[(size_t)(lane + 64) * 80] +
              sp[(size_t)(lane + 128) * 80];
#pragma unroll
    for (int o = 32; o >= 1; o >>= 1) x += __shfl_xor(x, o);
    if (lane == 0) ws[ACC_OFF + bb * 80 + idx] = x;
}

__device__ __forceinline__ void phaseC(const float* __restrict__ yp,
                                       const int* __restrict__ yt,
                                       float* __restrict__ ws,
                                       unsigned* __restrict__ hist,
                                       int blk, int tid) {
    int lane = tid & 63, wv = tid >> 6;
    __shared__ float ck_s[32];
    __shared__ float4 msw_s[17];
    __shared__ float part[4][2];
    int b = blk / NSB, xblk = blk - b * NSB;
    const float4* bp4 = (const float4*)(yp + (size_t)b * 5 * HWPIX);
    const int4* bt4 = (const int4*)(yt + (size_t)b * HWPIX);

    if (tid < 16) {
        int k = tid;
        const float* a = ws + ACC_OFF + (size_t)b * 80 + k * 5;
        float cnt = a[0];
        float safe = fmaxf(cnt, 1.0f);
        float inv = 1.0f / safe;
        ck_s[k * 2 + 0] = a[1] * inv;
        ck_s[k * 2 + 1] = a[2] * inv;
        float4 mw;
        mw.x = a[3] * inv;
        mw.y = a[4] * inv;
        mw.z = (cnt > 0.f) ? 0.5f / cnt : 0.f;
        mw.w = 0.f;
        msw_s[k] = mw;
    }
    if (tid == 16) msw_s[16] = (float4){0.f, 0.f, 0.f, 0.f};
    __syncthreads();

    f32x2 cky2[8], ckx2[8];
#pragma unroll
    for (int q = 0; q < 8; ++q) {
        cky2[q] = (f32x2){ck_s[4 * q], ck_s[4 * q + 2]};
        ckx2[q] = (f32x2){ck_s[4 * q + 1], ck_s[4 * q + 3]};
    }

    unsigned* hb = hist + (size_t)(b * Kdim) * 2 * NBINS;
    unsigned* posnh = hist + (size_t)NHIST;

    float varsum = 0.f, ssum = 0.f;
    for (int p = 0; p < 3; ++p) {
        int g = p * GPI + xblk * 256 + tid;
        float4 voy = bp4[g];
        float4 vox = bp4[g + Q4];
        float4 vsy = bp4[g + 2 * Q4];
        float4 vsx = bp4[g + 3 * Q4];
        float4 vse = bp4[g + 4 * Q4];
        int4 vt = bt4[g];
        int hwb = g * 4;
        float oy[4] = {voy.x, voy.y, voy.z, voy.w};
        float ox[4] = {vox.x, vox.y, vox.z, vox.w};
        float sya[4] = {vsy.x, vsy.y, vsy.z, vsy.w};
        float sxa[4] = {vsx.x, vsx.y, vsx.z, vsx.w};
        float sea[4] = {vse.x, vse.y, vse.z, vse.w};
        int tt[4] = {vt.x, vt.y, vt.z, vt.w};
#pragma unroll
        for (int j = 0; j < 4; ++j) {
            int hw = hwb + j;
            int h = hw / Wdim;
            int w = hw - h * Wdim;
            int own = tt[j] - 1;
            float sy = sya[j], sx = sxa[j];
            float ey = (float)h + oy[j], ex = (float)w + ox[j];
            float sby = fmaxf(sy, EPSf), sbx = fmaxf(sx, EPSf);
            float iy = 0.5f / (sby * sby), ix = 0.5f / (sbx * sbx);

            unsigned sm = 0;
#pragma unroll
            for (int q = 0; q < 8; ++q) {
                f32x2 dy2 = ey - cky2[q];
                f32x2 dx2 = ex - ckx2[q];
                f32x2 q2 = dy2 * dy2 * iy + dx2 * dx2 * ix;
                if (q2.x < QCLIP) sm |= (1u << (2 * q));
                if (q2.y < QCLIP) sm |= (1u << (2 * q + 1));
            }
            int ow = (own >= 0) ? own : 16;
            float4 mw = msw_s[ow];
            float devv = fabsf(sy - mw.x) + fabsf(sx - mw.y);
            varsum = fmaf(devv, mw.z, varsum);

            float st = (own >= 0) ? EPSf : 0.f;
            while (sm) {  // rare slow path: near some center
                int k = __ffs(sm) - 1;
                sm &= sm - 1;
                float dy = ey - ck_s[k * 2];
                float dx = ex - ck_s[k * 2 + 1];
                float q = fmaf(dy * dy, iy, dx * dx * ix);
                float phi = expf(-q);
                phi = fminf(fmaxf(phi, EPSf), 1.0f - EPSf);
                float lg = logf(phi) - log1pf(-phi);
                bool isPos = (k == own);
                float e;
                if (isPos) {
                    st = phi;
                    atomicAdd(&posnh[b * Kdim + k], 1u);
                    e = 1.0f - lg;
                } else {
                    e = 1.0f + lg;
                }
                if (e > 0.f) {
                    int bin = (int)(e * INV_BIN_W);
                    if (bin > NBINS - 1) bin = NBINS - 1;
                    atomicAdd(&hb[(k * 2 + (isPos ? 1 : 0)) * NBINS + bin], 1u);
                }
            }
            float dd = sea[j] - st;
            ssum = fmaf(dd, dd, ssum);
        }
    }
#pragma unroll
    for (int o = 32; o >= 1; o >>= 1) {
        varsum += __shfl_xor(varsum, o);
        ssum += __shfl_xor(ssum, o);
    }
    if (lane == 0) {
        part[wv][0] = varsum;
        part[wv][1] = ssum;
    }
    __syncthreads();
    if (tid < 2) {
        float v = part[0][tid] + part[1][tid] + part[2][tid] + part[3][tid];
        ws[MPART_OFF + (size_t)blk * 2 + tid] = v;
    }
}

__device__ __forceinline__ void phaseD(float* __restrict__ ws,
                                       const unsigned* __restrict__ hist,
                                       int blk, int tid) {
    if (blk >= 16) return;
    int wv = tid >> 6, lane = tid & 63;
    int i = blk * 4 + wv;  // 0..63
    float P = ws[ACC_OFF + i * 5];
    float res = 0.f;
    if (P >= 0.5f) {
        const unsigned* hn = hist + (size_t)i * 2 * NBINS;
        const unsigned* hp = hn + NBINS;
        const unsigned* posnh = hist + (size_t)NHIST;
        const float C_LO = logf(EPSf) - log1pf(-EPSf);
        const int HOTBIN = (int)((1.0f - C_LO) * INV_BIN_W);
        int deficit = (int)(P + 0.5f) - (int)posnh[i];
        int carry_p = 0, carry_n = 0;
        float Jtop = 0.f;
        float trap = 0.f;
        for (int c = NBINS / 64 - 1; c >= 0; --c) {
            int m = c * 64 + lane;
            int vp = (int)hp[m];
            int vn = (int)hn[m];
            if (m == HOTBIN) vp += deficit;
            for (int o = 1; o < 64; o <<= 1) {
                int tp = __shfl_down(vp, o);
                int tn = __shfl_down(vn, o);
                if (lane + o < 64) { vp += tp; vn += tn; }
            }
            float p_edge = (float)(carry_p + vp);
            float n_edge = (float)(carry_n + vn);
            float J = 1.0f - (P - p_edge) / (P + n_edge);
            float Jn = __shfl_down(J, 1);
            if (lane == 63) Jn = Jtop;
            trap += 0.5f * (J + Jn);
            carry_p += __shfl(vp, 0);
            carry_n += __shfl(vn, 0);
            Jtop = __shfl(J, 0);
        }
        for (int o = 1; o < 64; o <<= 1) {
            float t2 = __shfl_down(trap, o);
            if (lane + o < 64) trap += t2;
        }
        res = trap * BIN_W;
    }
    if (lane == 0) ws[LOVARR_OFF + i] = res;
}

// ======================= cooperative fused kernel ===========================

__global__ __launch_bounds__(256, 3) void k_all(const float* __restrict__ yp,
                                                const int* __restrict__ yt,
                                                float* __restrict__ ws,
                                                unsigned* __restrict__ hist) {
    cg::grid_group grid = cg::this_grid();
    int blk = blockIdx.x, tid = threadIdx.x;
    phaseA(yp, yt, ws, hist, blk, tid);
    grid.sync();
    phaseB(ws, blk, tid);
    grid.sync();
    phaseC(yp, yt, ws, hist, blk, tid);
    grid.sync();
    phaseD(ws, hist, blk, tid);
}

// ======================= fallback standalone kernels ========================

__global__ __launch_bounds__(256, 3) void kA(const float* __restrict__ yp,
                                             const int* __restrict__ yt,
                                             float* __restrict__ ws,
                                             unsigned* __restrict__ hist) {
    phaseA(yp, yt, ws, hist, blockIdx.x, threadIdx.x);
}
__global__ void kB(float* __restrict__ ws) {
    phaseB(ws, blockIdx.x, threadIdx.x);
}
__global__ __launch_bounds__(256, 3) void kC(const float* __restrict__ yp,
                                             const int* __restrict__ yt,
                                             float* __restrict__ ws,
                                             unsigned* __restrict__ hist) {
    phaseC(yp, yt, ws, hist, blockIdx.x, threadIdx.x);
}
__global__ void kD(float* __restrict__ ws, const unsigned* __restrict__ hist) {
    phaseD(ws, hist, blockIdx.x, threadIdx.x);
}

__global__ void k_final(const float* __restrict__ ws, float* __restrict__ out) {
    __shared__ float r0[256], r1[256], r2[256], r3[256];
    int t = threadIdx.x;
    float v = 0.f, s = 0.f, l = 0.f, pr = 0.f;
    for (int j = t; j < NBLK; j += 256) {
        v += ws[MPART_OFF + 2 * j];
        s += ws[MPART_OFF + 2 * j + 1];
    }
    if (t < 64) {
        l = ws[LOVARR_OFF + t];
        pr = (ws[ACC_OFF + t * 5] > 0.f) ? 1.f : 0.f;
    }
    r0[t] = v; r1[t] = s; r2[t] = l; r3[t] = pr;
    __syncthreads();
    for (int o = 128; o > 0; o >>= 1) {
        if (t < o) {
            r0[t] += r0[t + o]; r1[t] += r1[t + o];
            r2[t] += r2[t + o]; r3[t] += r3[t + o];
        }
        __syncthreads();
    }
    if (t == 0) {
        float npres = fmaxf(r3[0], 1.0f);
        out[0] = r2[0] / npres + 10.0f * (r0[0] / npres) +
                 r1[0] / (float)((size_t)Bdim * HWPIX);
    }
}

extern "C" void kernel_launch(void* const* d_in, const int* in_sizes, int n_in,
                              void* d_out, int out_size, void* d_ws, size_t ws_size,
                              hipStream_t stream) {
    const float* yp = (const float*)d_in[0];
    const int* yt = (const int*)d_in[1];
    float* ws = (float*)d_ws;
    unsigned* hist = (unsigned*)((char*)d_ws + HIST_OFF_F * 4);

    void* args[4] = {(void*)&yp, (void*)&yt, (void*)&ws, (void*)&hist};
    hipError_t err = hipLaunchCooperativeKernel((const void*)k_all, dim3(NBLK),
                                                dim3(256), args, 0, stream);
    if (err != hipSuccess) {
        (void)hipGetLastError();  // clear sticky error, fall back to split path
        kA<<<dim3(NBLK), 256, 0, stream>>>(yp, yt, ws, hist);
        kB<<<dim3(80), 256, 0, stream>>>(ws);
        kC<<<dim3(NBLK), 256, 0, stream>>>(yp, yt, ws, hist);
        kD<<<dim3(16), 256, 0, stream>>>(ws, hist);
    }
    k_final<<<1, 256, 0, stream>>>(ws, (float*)d_out);
}

// Round 9
// 82.743 us; speedup vs baseline: 3.3346x; 3.3346x over previous
//
#include <hip/hip_runtime.h>

#define HWPIX 589824
#define Wdim 768
#define Bdim 4
#define Kdim 16
#define NBINS 2048
#define RANGE_F 16.0f
#define BIN_W (RANGE_F / NBINS)
#define INV_BIN_W (NBINS / RANGE_F)
#define EPSf 1e-6f
#define QCLIP 13.8155106f   /* -log(1e-6): q >= QCLIP  <=>  phi clamps to EPS */

#define Q4 (HWPIX / 4)      // 147456 float4 groups per channel
#define NSB 192             // blocks per batch
#define NBLK (NSB * Bdim)   // 768 blocks
#define GPI (NSB * 256)     // float4-groups per p-iteration per batch

// ws float offsets
#define ACC_OFF 0                      // [B][K][5]
#define LOVARR_OFF 724                 // [64]
#define HIST_OFF_F 1024                // uint hist[B*K][2][NBINS]
#define NHIST (Bdim * Kdim * 2 * NBINS)
#define SPART_OFF (HIST_OFF_F + NHIST + 64)        // float [NBLK][80]
#define MPART_OFF (SPART_OFF + NBLK * 80)          // float [NBLK][2]

__global__ __launch_bounds__(256, 3) void k_stats(const float* __restrict__ yp,
                                                  const int* __restrict__ yt,
                                                  float* __restrict__ ws,
                                                  unsigned* __restrict__ hist) {
    int b = blockIdx.y;
    int lane = threadIdx.x & 63;
    int wv = threadIdx.x >> 6;
    __shared__ float lpart[4][80];

    // zero hist + posnh (folded memset; all 768 blocks participate)
    {
        int gtid = (b * NSB + blockIdx.x) * 256 + threadIdx.x;
        for (int i = gtid; i < NHIST + 64; i += NBLK * 256) hist[i] = 0u;
    }

    const float4* bp4 = (const float4*)(yp + (size_t)b * 5 * HWPIX);
    const int4* bt4 = (const int4*)(yt + (size_t)b * HWPIX);

    float acc[80];
#pragma unroll
    for (int v = 0; v < 80; ++v) acc[v] = 0.f;

    for (int p = 0; p < 3; ++p) {
        int g = p * GPI + blockIdx.x * 256 + threadIdx.x;
        float4 voy = bp4[g];
        float4 vox = bp4[g + Q4];
        float4 vsy = bp4[g + 2 * Q4];
        float4 vsx = bp4[g + 3 * Q4];
        int4 vt = bt4[g];
        int hwb = g * 4;
        float oy[4] = {voy.x, voy.y, voy.z, voy.w};
        float ox[4] = {vox.x, vox.y, vox.z, vox.w};
        float sy[4] = {vsy.x, vsy.y, vsy.z, vsy.w};
        float sx[4] = {vsx.x, vsx.y, vsx.z, vsx.w};
        int tt[4] = {vt.x, vt.y, vt.z, vt.w};
#pragma unroll
        for (int j = 0; j < 4; ++j) {
            int hw = hwb + j;
            int h = hw / Wdim;
            int w = hw - h * Wdim;
            int own = tt[j] - 1;
            float vy = (float)h + oy[j];
            float vx = (float)w + ox[j];
#pragma unroll
            for (int k = 0; k < Kdim; ++k) {
                float m = (own == k) ? 1.0f : 0.0f;
                acc[k * 5 + 0] += m;
                acc[k * 5 + 1] = fmaf(m, vy, acc[k * 5 + 1]);
                acc[k * 5 + 2] = fmaf(m, vx, acc[k * 5 + 2]);
                acc[k * 5 + 3] = fmaf(m, sy[j], acc[k * 5 + 3]);
                acc[k * 5 + 4] = fmaf(m, sx[j], acc[k * 5 + 4]);
            }
        }
    }

    // fold across half-waves: lanes 0-31 own values 0..39, lanes 32-63 own 40..79
    bool lo = (lane < 32);
#pragma unroll
    for (int v = 0; v < 40; ++v) {
        float send = lo ? acc[v + 40] : acc[v];
        float got = __shfl_xor(send, 32);
        acc[v] += lo ? got : 0.f;
        acc[v + 40] += lo ? 0.f : got;
    }
#pragma unroll
    for (int v = 0; v < 40; ++v) {
        float x = lo ? acc[v] : acc[v + 40];
#pragma unroll
        for (int o = 16; o >= 1; o >>= 1) x += __shfl_xor(x, o);
        if ((lane & 31) == 0) lpart[wv][lo ? v : v + 40] = x;
    }
    __syncthreads();
    if (threadIdx.x < 80) {
        float v = lpart[0][threadIdx.x] + lpart[1][threadIdx.x] +
                  lpart[2][threadIdx.x] + lpart[3][threadIdx.x];
        ws[SPART_OFF + (size_t)(b * NSB + blockIdx.x) * 80 + threadIdx.x] = v;
    }
}

// 80 blocks x 256: one wave per output (320 outputs); lane sums 3 strided
// partials, butterfly-reduces, lane 0 stores ACC.
__global__ void k_centers2(float* __restrict__ ws) {
    int wv = threadIdx.x >> 6;
    int lane = threadIdx.x & 63;
    int gw = blockIdx.x * 4 + wv;        // 0..319
    int b = gw / 80, idx = gw - b * 80;
    const float* sp = ws + SPART_OFF + (size_t)b * NSB * 80 + idx;
    float x = sp[(size_t)lane * 80] + sp[(size_t)(lane + 64) * 80] +
              sp[(size_t)(lane + 128) * 80];
#pragma unroll
    for (int o = 32; o >= 1; o >>= 1) x += __shfl_xor(x, o);
    if (lane == 0) ws[ACC_OFF + b * 80 + idx] = x;
}

__global__ __launch_bounds__(256, 3) void k_main(const float* __restrict__ yp,
                                                 const int* __restrict__ yt,
                                                 float* __restrict__ ws,
                                                 unsigned* __restrict__ hist) {
    int b = blockIdx.y;
    int lane = threadIdx.x & 63;
    int wv = threadIdx.x >> 6;
    __shared__ float ck_s[32];
    __shared__ float4 msw_s[17];
    __shared__ float part[4][2];
    // prologue: compute centers/means/weights for this batch from ACC
    if (threadIdx.x < 16) {
        int k = threadIdx.x;
        const float* a = ws + ACC_OFF + (size_t)b * 80 + k * 5;
        float cnt = a[0];
        float safe = fmaxf(cnt, 1.0f);
        float inv = 1.0f / safe;
        ck_s[k * 2 + 0] = a[1] * inv;
        ck_s[k * 2 + 1] = a[2] * inv;
        float4 mw;
        mw.x = a[3] * inv;
        mw.y = a[4] * inv;
        mw.z = (cnt > 0.f) ? 0.5f / cnt : 0.f;
        mw.w = 0.f;
        msw_s[k] = mw;
    }
    if (threadIdx.x == 16) msw_s[16] = (float4){0.f, 0.f, 0.f, 0.f};
    __syncthreads();

    float cky[Kdim], ckx[Kdim];
#pragma unroll
    for (int k = 0; k < Kdim; ++k) {
        cky[k] = ck_s[k * 2];
        ckx[k] = ck_s[k * 2 + 1];
    }

    unsigned* hb = hist + (size_t)(b * Kdim) * 2 * NBINS;
    unsigned* posnh = hist + (size_t)NHIST;
    const float4* bp4 = (const float4*)(yp + (size_t)b * 5 * HWPIX);
    const int4* bt4 = (const int4*)(yt + (size_t)b * HWPIX);

    float varsum = 0.f, ssum = 0.f;
    for (int p = 0; p < 3; ++p) {
        int g = p * GPI + blockIdx.x * 256 + threadIdx.x;
        float4 voy = bp4[g];
        float4 vox = bp4[g + Q4];
        float4 vsy = bp4[g + 2 * Q4];
        float4 vsx = bp4[g + 3 * Q4];
        float4 vse = bp4[g + 4 * Q4];
        int4 vt = bt4[g];
        int hwb = g * 4;
        float oy[4] = {voy.x, voy.y, voy.z, voy.w};
        float ox[4] = {vox.x, vox.y, vox.z, vox.w};
        float sya[4] = {vsy.x, vsy.y, vsy.z, vsy.w};
        float sxa[4] = {vsx.x, vsx.y, vsx.z, vsx.w};
        float sea[4] = {vse.x, vse.y, vse.z, vse.w};
        int tt[4] = {vt.x, vt.y, vt.z, vt.w};
#pragma unroll
        for (int j = 0; j < 4; ++j) {
            int hw = hwb + j;
            int h = hw / Wdim;
            int w = hw - h * Wdim;
            int own = tt[j] - 1;
            float sy = sya[j], sx = sxa[j];
            float ey = (float)h + oy[j], ex = (float)w + ox[j];
            float sby = fmaxf(sy, EPSf), sbx = fmaxf(sx, EPSf);
            float iy = 0.5f / (sby * sby), ix = 0.5f / (sbx * sbx);

            unsigned sm = 0;
#pragma unroll
            for (int k = 0; k < Kdim; ++k) {
                float dy = ey - cky[k];
                float dx = ex - ckx[k];
                float q = fmaf(dy * dy, iy, dx * dx * ix);
                if (q < QCLIP) sm |= (1u << k);
            }
            // dev + var contribution (slot 16 = zeros for unlabeled)
            int ow = (own >= 0) ? own : 16;
            float4 mw = msw_s[ow];
            float devv = fabsf(sy - mw.x) + fabsf(sx - mw.y);
            varsum = fmaf(devv, mw.z, varsum);

            float st = (own >= 0) ? EPSf : 0.f;
            while (sm) {  // rare slow path: near some center
                int k = __ffs(sm) - 1;
                sm &= sm - 1;
                float dy = ey - ck_s[k * 2];
                float dx = ex - ck_s[k * 2 + 1];
                float q = fmaf(dy * dy, iy, dx * dx * ix);
                float phi = expf(-q);
                phi = fminf(fmaxf(phi, EPSf), 1.0f - EPSf);
                float lg = logf(phi) - log1pf(-phi);
                bool isPos = (k == own);
                float e;
                if (isPos) {
                    st = phi;
                    atomicAdd(&posnh[b * Kdim + k], 1u);
                    e = 1.0f - lg;
                } else {
                    e = 1.0f + lg;
                }
                if (e > 0.f) {
                    int bin = (int)(e * INV_BIN_W);
                    if (bin > NBINS - 1) bin = NBINS - 1;
                    atomicAdd(&hb[(k * 2 + (isPos ? 1 : 0)) * NBINS + bin], 1u);
                }
            }
            float dd = sea[j] - st;
            ssum = fmaf(dd, dd, ssum);
        }
    }
#pragma unroll
    for (int o = 32; o >= 1; o >>= 1) {
        varsum += __shfl_xor(varsum, o);
        ssum += __shfl_xor(ssum, o);
    }
    if (lane == 0) {
        part[wv][0] = varsum;
        part[wv][1] = ssum;
    }
    __syncthreads();
    if (threadIdx.x < 2) {
        float v = part[0][threadIdx.x] + part[1][threadIdx.x] +
                  part[2][threadIdx.x] + part[3][threadIdx.x];
        ws[MPART_OFF + (size_t)(b * NSB + blockIdx.x) * 2 + threadIdx.x] = v;
    }
}

// One wave per (b,k): suffix-scan histogram top-down, trapezoid-integrate
// J(t) = 1 - (P - p(t))/(P + n(t)).  Clamped positives enter implicitly as
// deficit = P - posnh at HOTBIN.
__global__ void k_lovasz(float* __restrict__ ws, const unsigned* __restrict__ hist) {
    int i = blockIdx.x;  // 0..63
    int lane = threadIdx.x;
    float P = ws[ACC_OFF + i * 5];
    if (P < 0.5f) {
        if (lane == 0) ws[LOVARR_OFF + i] = 0.f;
        return;
    }
    const unsigned* hn = hist + (size_t)i * 2 * NBINS;
    const unsigned* hp = hn + NBINS;
    const unsigned* posnh = hist + (size_t)NHIST;
    const float C_LO = logf(EPSf) - log1pf(-EPSf);
    const int HOTBIN = (int)((1.0f - C_LO) * INV_BIN_W);
    int deficit = (int)(P + 0.5f) - (int)posnh[i];
    int carry_p = 0, carry_n = 0;
    float Jtop = 0.f;
    float trap = 0.f;
    for (int c = NBINS / 64 - 1; c >= 0; --c) {
        int m = c * 64 + lane;
        int vp = (int)hp[m];
        int vn = (int)hn[m];
        if (m == HOTBIN) vp += deficit;
        for (int o = 1; o < 64; o <<= 1) {
            int tp = __shfl_down(vp, o);
            int tn = __shfl_down(vn, o);
            if (lane + o < 64) { vp += tp; vn += tn; }
        }
        float p_edge = (float)(carry_p + vp);
        float n_edge = (float)(carry_n + vn);
        float J = 1.0f - (P - p_edge) / (P + n_edge);
        float Jn = __shfl_down(J, 1);
        if (lane == 63) Jn = Jtop;
        trap += 0.5f * (J + Jn);
        carry_p += __shfl(vp, 0);
        carry_n += __shfl(vn, 0);
        Jtop = __shfl(J, 0);
    }
    for (int o = 1; o < 64; o <<= 1) {
        float t2 = __shfl_down(trap, o);
        if (lane + o < 64) trap += t2;
    }
    if (lane == 0) ws[LOVARR_OFF + i] = trap * BIN_W;
}

__global__ void k_final(const float* __restrict__ ws, float* __restrict__ out) {
    __shared__ float r0[256], r1[256], r2[256], r3[256];
    int t = threadIdx.x;
    float v = 0.f, s = 0.f, l = 0.f, pr = 0.f;
    for (int j = t; j < NBLK; j += 256) {
        v += ws[MPART_OFF + 2 * j];
        s += ws[MPART_OFF + 2 * j + 1];
    }
    if (t < 64) {
        l = ws[LOVARR_OFF + t];
        pr = (ws[ACC_OFF + t * 5] > 0.f) ? 1.f : 0.f;
    }
    r0[t] = v; r1[t] = s; r2[t] = l; r3[t] = pr;
    __syncthreads();
    for (int o = 128; o > 0; o >>= 1) {
        if (t < o) {
            r0[t] += r0[t + o]; r1[t] += r1[t + o];
            r2[t] += r2[t + o]; r3[t] += r3[t + o];
        }
        __syncthreads();
    }
    if (t == 0) {
        float npres = fmaxf(r3[0], 1.0f);
        out[0] = r2[0] / npres + 10.0f * (r0[0] / npres) +
                 r1[0] / (float)((size_t)Bdim * HWPIX);
    }
}

extern "C" void kernel_launch(void* const* d_in, const int* in_sizes, int n_in,
                              void* d_out, int out_size, void* d_ws, size_t ws_size,
                              hipStream_t stream) {
    const float* yp = (const float*)d_in[0];
    const int* yt = (const int*)d_in[1];
    float* ws = (float*)d_ws;
    unsigned* hist = (unsigned*)((char*)d_ws + HIST_OFF_F * 4);

    dim3 g(NSB, Bdim);
    k_stats<<<g, 256, 0, stream>>>(yp, yt, ws, hist);
    k_centers2<<<80, 256, 0, stream>>>(ws);
    k_main<<<g, 256, 0, stream>>>(yp, yt, ws, hist);
    k_lovasz<<<64, 64, 0, stream>>>(ws, hist);
    k_final<<<1, 256, 0, stream>>>(ws, (float*)d_out);
}